// Round 4
// baseline (557.602 us; speedup 1.0000x reference)
//
#include <hip/hip_runtime.h>

// Guided filter r=8, eps=1e-4, (1,3,4096,4096) fp32.
// Wave-autonomous streaming, 2 columns per lane (packed fp32), NO row buffer:
//  - lane owns adjacent column pair (2l, 2l+1); 128 cols/wave, 112 outputs
//  - vertical 17-row running sums in 8 registers; the outgoing row (y-9) and
//    the center row (y, for icur) are RE-READ from L2/L3 (identical fp32 bits
//    -> running-sum add/subtract cancels exactly). This removes the 68-reg
//    circular buffer that previously forced 4 waves/SIMD (AGPR overflow).
//  - horizontal 17-tap window from ONE wave scan of pair-sums:
//      CP(2l+1) = P(l), CP(2l) = P(l) - v1(l) = Q(l)
//      w(2l)   = Q(l+4) - [l>=5] P(l-5)
//      w(2l+1) = P(l+4) - [l>=4] Q(l-4)
//  - all 5 loads for row t+1 issued before row t's scan/epilogue (1-row
//    software prefetch; evict/center re-reads are L2-hot)

typedef float v2f __attribute__((ext_vector_type(2)));

#define HH   4096
#define WW   4096
#define CC   3
#define RAD  8
#define LOG2W 12
#define OUTC 112           // output columns per wave
#define ROWS 24            // output rows per wave tile
#define CS   37            // ceil(4096/112) column strips
#define RS   171           // ceil(4096/24) row strips
#define TOTALW (CC*CS*RS)  // 18981
#define WPB  4             // waves per 256-thread block
#define EPS  1e-4f

// Four wave64 inclusive prefix sums, fused-DPP, 4-way interleaved (proven r2/r3).
__device__ __forceinline__ void scan4(float si, float sp, float spi, float sii,
                                      float& a, float& b, float& c, float& d) {
    asm("v_mov_b32 %0, %4\n\t"
        "v_mov_b32 %1, %5\n\t"
        "v_mov_b32 %2, %6\n\t"
        "v_mov_b32 %3, %7\n\t"
        "v_add_f32_dpp %0, %0, %0 row_shr:1 row_mask:0xf bank_mask:0xf bound_ctrl:0\n\t"
        "v_add_f32_dpp %1, %1, %1 row_shr:1 row_mask:0xf bank_mask:0xf bound_ctrl:0\n\t"
        "v_add_f32_dpp %2, %2, %2 row_shr:1 row_mask:0xf bank_mask:0xf bound_ctrl:0\n\t"
        "v_add_f32_dpp %3, %3, %3 row_shr:1 row_mask:0xf bank_mask:0xf bound_ctrl:0\n\t"
        "v_add_f32_dpp %0, %0, %0 row_shr:2 row_mask:0xf bank_mask:0xf bound_ctrl:0\n\t"
        "v_add_f32_dpp %1, %1, %1 row_shr:2 row_mask:0xf bank_mask:0xf bound_ctrl:0\n\t"
        "v_add_f32_dpp %2, %2, %2 row_shr:2 row_mask:0xf bank_mask:0xf bound_ctrl:0\n\t"
        "v_add_f32_dpp %3, %3, %3 row_shr:2 row_mask:0xf bank_mask:0xf bound_ctrl:0\n\t"
        "v_add_f32_dpp %0, %0, %0 row_shr:4 row_mask:0xf bank_mask:0xf bound_ctrl:0\n\t"
        "v_add_f32_dpp %1, %1, %1 row_shr:4 row_mask:0xf bank_mask:0xf bound_ctrl:0\n\t"
        "v_add_f32_dpp %2, %2, %2 row_shr:4 row_mask:0xf bank_mask:0xf bound_ctrl:0\n\t"
        "v_add_f32_dpp %3, %3, %3 row_shr:4 row_mask:0xf bank_mask:0xf bound_ctrl:0\n\t"
        "v_add_f32_dpp %0, %0, %0 row_shr:8 row_mask:0xf bank_mask:0xf bound_ctrl:0\n\t"
        "v_add_f32_dpp %1, %1, %1 row_shr:8 row_mask:0xf bank_mask:0xf bound_ctrl:0\n\t"
        "v_add_f32_dpp %2, %2, %2 row_shr:8 row_mask:0xf bank_mask:0xf bound_ctrl:0\n\t"
        "v_add_f32_dpp %3, %3, %3 row_shr:8 row_mask:0xf bank_mask:0xf bound_ctrl:0\n\t"
        "v_add_f32_dpp %0, %0, %0 row_bcast:15 row_mask:0xa bank_mask:0xf\n\t"
        "v_add_f32_dpp %1, %1, %1 row_bcast:15 row_mask:0xa bank_mask:0xf\n\t"
        "v_add_f32_dpp %2, %2, %2 row_bcast:15 row_mask:0xa bank_mask:0xf\n\t"
        "v_add_f32_dpp %3, %3, %3 row_bcast:15 row_mask:0xa bank_mask:0xf\n\t"
        "v_add_f32_dpp %0, %0, %0 row_bcast:31 row_mask:0xc bank_mask:0xf\n\t"
        "v_add_f32_dpp %1, %1, %1 row_bcast:31 row_mask:0xc bank_mask:0xf\n\t"
        "v_add_f32_dpp %2, %2, %2 row_bcast:31 row_mask:0xc bank_mask:0xf\n\t"
        "v_add_f32_dpp %3, %3, %3 row_bcast:31 row_mask:0xc bank_mask:0xf"
        : "=&v"(a), "=&v"(b), "=&v"(c), "=&v"(d)
        : "v"(si), "v"(sp), "v"(spi), "v"(sii));
}

__device__ __forceinline__ float bper(int addr, float x) {
    return __int_as_float(__builtin_amdgcn_ds_bpermute(addr, __float_as_int(x)));
}

__global__ __launch_bounds__(256, 6)
void gf_stream_kernel(const float* __restrict__ gi,
                      const float* __restrict__ gp,
                      float* __restrict__ gq) {
    const int lane = threadIdx.x & 63;
    const int wid  = __builtin_amdgcn_readfirstlane(blockIdx.x * WPB + (threadIdx.x >> 6));
    if (wid >= TOTALW) return;             // wave-uniform tail exit (no barriers anywhere)

    const int c   = wid / (CS * RS);
    const int rm  = wid - c * (CS * RS);
    const int rs  = rm / CS;
    const int cs  = rm - rs * CS;
    const int xb  = cs * OUTC - RAD;       // strip base column; always even
    const int y0  = rs * ROWS;

    const size_t plane = (size_t)HH << LOG2W;
    const float* Ic = gi + (size_t)c * plane;
    const float* Pc = gp + (size_t)c * plane;
    float*       Qc = gq + (size_t)c * plane;

    // column pair: gx0 = xb + 2*lane (even). Pair is valid all-or-nothing.
    const int  gx0 = xb + 2 * lane;
    const bool pv  = (gx0 >= 0) && (gx0 < WW);
    const int  gxc = min(max(gx0, 0), WW - 2);      // clamped dwordx2-safe base
    const bool outok = (lane >= 4) && (lane < 60) && pv;

    // bpermute byte addresses + border masks for the window taps
    const int   adn = ((lane + 4) & 63) << 2;
    const int   au5 = ((lane - 5) & 63) << 2;
    const int   au4 = ((lane - 4) & 63) << 2;
    const float m5  = (lane >= 5) ? -1.0f : 0.0f;
    const float m4  = (lane >= 4) ? -1.0f : 0.0f;

    const int gx1 = gx0 + 1;
    const int nx0 = min(gx0 + RAD, WW - 1) - max(gx0 - RAD, 0) + 1;
    const int nx1 = min(gx1 + RAD, WW - 1) - max(gx1 - RAD, 0) + 1;
    v2f invnx;
    invnx.x = __builtin_amdgcn_rcpf((float)max(nx0, 1));
    invnx.y = __builtin_amdgcn_rcpf((float)max(nx1, 1));

    const v2f zero = {0.f, 0.f};
    v2f vsi = zero, vsp = zero, vspi = zero, vsii = zero;
    v2f cicur = zero;                      // I at current output row (masked)

    // ---- init: accumulate rows y0-8 .. y0+8 into running sums (no buffer) ----
#pragma unroll
    for (int k = 0; k < 17; ++k) {
        int yy = y0 - RAD + k;
        v2f a = zero, b = zero;
        if (yy >= 0 && yy < HH) {          // wave-uniform
            const float* rI = Ic + ((size_t)(unsigned)yy << LOG2W);
            const float* rP = Pc + ((size_t)(unsigned)yy << LOG2W);
            v2f av = *reinterpret_cast<const v2f*>(rI + gxc);
            v2f bv = *reinterpret_cast<const v2f*>(rP + gxc);
            a = pv ? av : zero;
            b = pv ? bv : zero;
        }
        if (k == RAD) cicur = a;           // I(y0), already masked
        vsi += a; vsp += b;
        vspi = __builtin_elementwise_fma(a, b, vspi);
        vsii = __builtin_elementwise_fma(a, a, vsii);
    }

    // prefetch state for the NEXT row's update:
    //   pf_oa/pf_ob = I,P at evict row (y-9); pf_fa/pf_fb = I,P at fresh row
    //   (y+8); pf_ci = I at center row y. Evict/center are L2/L3-hot re-reads.
    v2f pf_oa = zero, pf_ob = zero, pf_fa = zero, pf_fb = zero, pf_ci = zero;

    // ---- emit one output row (pair of output columns per lane) ----
    auto emit = [&](int y, v2f icur) {
        float psi  = vsi.x  + vsi.y;
        float psp  = vsp.x  + vsp.y;
        float pspi = vspi.x + vspi.y;
        float psii = vsii.x + vsii.y;
        float Pi_, Pp_, Ppi_, Pii_;
        scan4(psi, psp, pspi, psii, Pi_, Pp_, Ppi_, Pii_);
        float Qi_  = Pi_  - vsi.y;         // CP at this lane's even column
        float Qp_  = Pp_  - vsp.y;
        float Qpi_ = Ppi_ - vspi.y;
        float Qii_ = Pii_ - vsii.y;

        auto taps = [&](float P_, float Q_) -> v2f {
            float qdn = bper(adn, Q_);     // CP(2l+8)
            float pdn = bper(adn, P_);     // CP(2l+9)
            float pu5 = bper(au5, P_);     // CP(2l-9)
            float qu4 = bper(au4, Q_);     // CP(2l-8)
            v2f w;
            w.x = fmaf(m5, pu5, qdn);      // window for col 2l
            w.y = fmaf(m4, qu4, pdn);      // window for col 2l+1
            return w;
        };
        v2f wi  = taps(Pi_,  Qi_);
        v2f wp  = taps(Pp_,  Qp_);
        v2f wpi = taps(Ppi_, Qpi_);
        v2f wii = taps(Pii_, Qii_);

        int   ny  = min(y + RAD, HH - 1) - max(y - RAD, 0) + 1;   // uniform
        float iny = __builtin_amdgcn_rcpf((float)ny);
        v2f invN  = invnx * iny;
        v2f mi  = wi  * invN;
        v2f mp  = wp  * invN;
        v2f mpi = wpi * invN;
        v2f mii = wii * invN;
        v2f cip = __builtin_elementwise_fma(-mp, mi, mpi);
        v2f cii = __builtin_elementwise_fma(-mi, mi, mii);
        v2f den = cii + EPS;
        v2f ra;
        ra.x = __builtin_amdgcn_rcpf(den.x);
        ra.y = __builtin_amdgcn_rcpf(den.y);
        v2f aa = cip * ra;
        v2f bb = __builtin_elementwise_fma(-aa, mi, mp);
        v2f q  = __builtin_elementwise_fma(aa, icur, bb);
        q = __builtin_elementwise_min(__builtin_elementwise_max(q, zero), (v2f){1.f, 1.f});
        if (outok) {
            float* Qrow = Qc + ((size_t)(unsigned)y << LOG2W);
            *reinterpret_cast<v2f*>(Qrow + gx0) = q;
        }
    };

    int y = y0;
#pragma unroll 1
    for (int t = 0; t < ROWS; ++t, ++y) {
        if (y >= HH) break;                // wave-uniform (bottom strip trims)

        if (t) {
            // consume prefetched rows for THIS row's window slide.
            // evict row y-9: re-read of the exact bits added 17 steps ago ->
            // products recomputed identically -> exact cancellation.
            v2f a0 = pv ? pf_oa : zero;
            v2f b0 = pv ? pf_ob : zero;
            vsi -= a0; vsp -= b0;
            vspi = __builtin_elementwise_fma(-a0, b0, vspi);
            vsii = __builtin_elementwise_fma(-a0, a0, vsii);
            v2f na = pv ? pf_fa : zero;
            v2f nb = pv ? pf_fb : zero;
            vsi += na; vsp += nb;
            vspi = __builtin_elementwise_fma(na, nb, vspi);
            vsii = __builtin_elementwise_fma(na, na, vsii);
            cicur = pv ? pf_ci : zero;
        }

        // issue all 5 loads for row y+1 BEFORE this row's scan/epilogue so
        // their latency hides under ~250 issue-cycles of compute.
        {
            int yn = y + 1;
            pf_oa = zero; pf_ob = zero; pf_fa = zero; pf_fb = zero;
            if (yn < HH) {                 // wave-uniform
                const float* rC = Ic + ((size_t)(unsigned)yn << LOG2W);
                pf_ci = *reinterpret_cast<const v2f*>(rC + gxc);
                int ye = yn - (RAD + 1);
                if (ye >= 0) {             // wave-uniform
                    const float* rI = Ic + ((size_t)(unsigned)ye << LOG2W);
                    const float* rP = Pc + ((size_t)(unsigned)ye << LOG2W);
                    pf_oa = *reinterpret_cast<const v2f*>(rI + gxc);
                    pf_ob = *reinterpret_cast<const v2f*>(rP + gxc);
                }
                int yf = yn + RAD;
                if (yf < HH) {             // wave-uniform
                    const float* rI = Ic + ((size_t)(unsigned)yf << LOG2W);
                    const float* rP = Pc + ((size_t)(unsigned)yf << LOG2W);
                    pf_fa = *reinterpret_cast<const v2f*>(rI + gxc);
                    pf_fb = *reinterpret_cast<const v2f*>(rP + gxc);
                }
            }
        }

        emit(y, cicur);
    }
}

extern "C" void kernel_launch(void* const* d_in, const int* in_sizes, int n_in,
                              void* d_out, int out_size, void* d_ws, size_t ws_size,
                              hipStream_t stream) {
    const float* gi = (const float*)d_in[0];
    const float* gp = (const float*)d_in[1];
    float* gq = (float*)d_out;
    const int blocks = (TOTALW + WPB - 1) / WPB;   // 4746
    gf_stream_kernel<<<blocks, 256, 0, stream>>>(gi, gp, gq);
}